// Round 2
// baseline (113.097 us; speedup 1.0000x reference)
//
#include <hip/hip_runtime.h>
#include <hip/hip_bf16.h>
#include <cstdint>
#include <cstddef>

typedef float  f32x4  __attribute__((ext_vector_type(4)));
typedef __bf16 bf16x8 __attribute__((ext_vector_type(8)));
typedef __bf16 bf16x4 __attribute__((ext_vector_type(4)));

#define MFMA(a, b, c) __builtin_amdgcn_mfma_f32_16x16x32_bf16((a), (b), (c), 0, 0, 0)

#define B_     8
#define S_     2048
#define D_     1024
#define E_     64
#define YSZ    (B_ * S_ * D_)   // 16777216
#define KTR    16               // truncation depth: rho^16 ~ 2e-7

// ---------------- k_setup: convert weights to bf16 ----------------
__global__ __launch_bounds__(256) void k_setup(const float* __restrict__ w_in,
                                               const float* __restrict__ w_out,
                                               __bf16* __restrict__ winb,
                                               __bf16* __restrict__ wob) {
  const int i = blockIdx.x * 256 + threadIdx.x;   // grid 256 -> 65536 threads
  winb[i] = (__bf16)w_in[i];
  wob[i]  = (__bf16)w_out[i];
}

// ---------------- k_beta: beta = x @ w_in^T  (16384x1024x64) ----------------
__global__ __launch_bounds__(256) void k_beta(const float* __restrict__ x,
                                              const __bf16* __restrict__ winb,
                                              float* __restrict__ beta) {
  const int tid = threadIdx.x;
  const int w = tid >> 6, lane = tid & 63;
  const int u = lane >> 4, fl = lane & 15;
  const int rowA = blockIdx.x * 64 + w * 16 + fl;
  const float*  xp = x + (size_t)rowA * 1024 + u * 8;
  const __bf16* wp = winb + fl * 1024 + u * 8;

  f32x4  acc[4] = {};
  f32x4  xc[2][2], xn[2][2];
  bf16x8 bc[4][2], bn[4][2];

#pragma unroll
  for (int kt = 0; kt < 2; kt++) {
    xc[kt][0] = *(const f32x4*)(xp + kt * 32);
    xc[kt][1] = *(const f32x4*)(xp + kt * 32 + 4);
  }
#pragma unroll
  for (int ct = 0; ct < 4; ct++)
#pragma unroll
    for (int kt = 0; kt < 2; kt++)
      bc[ct][kt] = *(const bf16x8*)(wp + ct * 16384 + kt * 32);

#pragma unroll
  for (int kk = 0; kk < 16; kk++) {
    if (kk < 15) {
      const int k1 = (kk + 1) * 64;
#pragma unroll
      for (int kt = 0; kt < 2; kt++) {
        xn[kt][0] = *(const f32x4*)(xp + k1 + kt * 32);
        xn[kt][1] = *(const f32x4*)(xp + k1 + kt * 32 + 4);
      }
#pragma unroll
      for (int ct = 0; ct < 4; ct++)
#pragma unroll
        for (int kt = 0; kt < 2; kt++)
          bn[ct][kt] = *(const bf16x8*)(wp + ct * 16384 + k1 + kt * 32);
    }
    bf16x8 af[2];
#pragma unroll
    for (int kt = 0; kt < 2; kt++)
#pragma unroll
      for (int j = 0; j < 4; j++) {
        af[kt][j]     = (__bf16)xc[kt][0][j];
        af[kt][j + 4] = (__bf16)xc[kt][1][j];
      }
#pragma unroll
    for (int ct = 0; ct < 4; ct++) {
      acc[ct] = MFMA(af[0], bc[ct][0], acc[ct]);
      acc[ct] = MFMA(af[1], bc[ct][1], acc[ct]);
    }
    if (kk < 15) {
#pragma unroll
      for (int kt = 0; kt < 2; kt++) { xc[kt][0] = xn[kt][0]; xc[kt][1] = xn[kt][1]; }
#pragma unroll
      for (int ct = 0; ct < 4; ct++) { bc[ct][0] = bn[ct][0]; bc[ct][1] = bn[ct][1]; }
    }
  }

  const int rowC = blockIdx.x * 64 + w * 16 + u * 4;
#pragma unroll
  for (int ct = 0; ct < 4; ct++)
#pragma unroll
    for (int r = 0; r < 4; r++)
      beta[(size_t)(rowC + r) * 64 + ct * 16 + fl] = acc[ct][r];
}

// ---------------- k_impulse: C_k = R(ΛR)^k via impulse responses ----------------
// 4 blocks x 64 thr; block owns 16 impulse columns e = blockIdx*16 + fl.
// Step machinery identical to the validated round-0 scan. After step s, state = C_s.
// Stores: Gt[f][s*64+e] = Re(C_s[e][f]) (bf16, conv B-operand layout),
//         CkR/CkI[s][f][e] (f32, for the final-state kernel).
__global__ __launch_bounds__(64) void k_impulse(const float* __restrict__ resonance,
                                                const float* __restrict__ alpha,
                                                const float* __restrict__ omega,
                                                __bf16* __restrict__ Gt,
                                                float* __restrict__ CkR,
                                                float* __restrict__ CkI) {
  const int lane = threadIdx.x;
  const int u = lane >> 4, fl = lane & 15;
  const int ecol = blockIdx.x * 16 + fl;

  bf16x8 afr[4][2];   // A[f][e] = R[e][f] - (e==f)
#pragma unroll
  for (int mt = 0; mt < 4; mt++)
#pragma unroll
    for (int kt = 0; kt < 2; kt++)
#pragma unroll
      for (int j = 0; j < 8; j++) {
        const int e = kt * 32 + u * 8 + j;
        const int f = mt * 16 + fl;
        float v = resonance[e * 64 + f];
        if (e == f) v -= 1.0f;
        afr[mt][kt][j] = (__bf16)v;
      }

  float mcv[4][4], msv[4][4];
#pragma unroll
  for (int mt = 0; mt < 4; mt++)
#pragma unroll
    for (int r = 0; r < 4; r++) {
      const int fr = mt * 16 + u * 4 + r;
      const float mg = 1.0f / (1.0f + expf(-alpha[fr]));
      mcv[mt][r] = mg * cosf(omega[fr]);
      msv[mt][r] = mg * sinf(omega[fr]);
    }

  __shared__ __bf16 lsr[16][72];
  __shared__ __bf16 lsi[16][72];

  f32x4 sr[4] = {}, si[4] = {};

  for (int s = 0; s < KTR; s++) {
    f32x4 rr[4], ri[4];
#pragma unroll
    for (int mt = 0; mt < 4; mt++)
#pragma unroll
      for (int r = 0; r < 4; r++) {
        const float bt = (s == 0 && (mt * 16 + u * 4 + r) == ecol) ? 1.0f : 0.0f;
        rr[mt][r] = mcv[mt][r] * sr[mt][r] - msv[mt][r] * si[mt][r] + bt;
        ri[mt][r] = msv[mt][r] * sr[mt][r] + mcv[mt][r] * si[mt][r];
      }
#pragma unroll
    for (int mt = 0; mt < 4; mt++) {
      bf16x4 pr, pi;
#pragma unroll
      for (int r = 0; r < 4; r++) { pr[r] = (__bf16)rr[mt][r]; pi[r] = (__bf16)ri[mt][r]; }
      *(bf16x4*)&lsr[fl][mt * 16 + u * 4] = pr;
      *(bf16x4*)&lsi[fl][mt * 16 + u * 4] = pi;
    }
    __syncthreads();
    bf16x8 brf[2], bif[2];
#pragma unroll
    for (int kt = 0; kt < 2; kt++) {
      brf[kt] = *(const bf16x8*)&lsr[fl][kt * 32 + u * 8];
      bif[kt] = *(const bf16x8*)&lsi[fl][kt * 32 + u * 8];
    }
#pragma unroll
    for (int mt = 0; mt < 4; mt++) {
      f32x4 dr = MFMA(afr[mt][0], brf[0], rr[mt]);
      sr[mt]   = MFMA(afr[mt][1], brf[1], dr);
      f32x4 di = MFMA(afr[mt][0], bif[0], ri[mt]);
      si[mt]   = MFMA(afr[mt][1], bif[1], di);
    }
    // state now equals C_s; store it
#pragma unroll
    for (int mt = 0; mt < 4; mt++)
#pragma unroll
      for (int r = 0; r < 4; r++) {
        const int f = mt * 16 + u * 4 + r;
        Gt[f * 1024 + s * 64 + ecol]  = (__bf16)sr[mt][r];
        CkR[s * 4096 + f * 64 + ecol] = sr[mt][r];
        CkI[s * 4096 + f * 64 + ecol] = si[mt][r];
      }
    __syncthreads();
  }
}

// ---------------- k_conv: states[t] = sum_k beta[t-k] @ G_k ----------------
// Banded-Toeplitz GEMM, K = KTR*64 = 1024. Structural clone of k_beta:
// A row pointer shifts by -kk rows per 64-wide K chunk (chunk kk <-> lag k=kk),
// zero-masked where t-k < 0 (exact for t < KTR).
__global__ __launch_bounds__(256) void k_conv(const float* __restrict__ beta,
                                              const __bf16* __restrict__ Gt,
                                              __bf16* __restrict__ states) {
  const int tid = threadIdx.x;
  const int w = tid >> 6, lane = tid & 63;
  const int u = lane >> 4, fl = lane & 15;
  const int rowA = blockIdx.x * 64 + w * 16 + fl;
  const int tloc = rowA & (S_ - 1);
  const float*  xp = beta + (size_t)rowA * 64 + u * 8;
  const __bf16* wp = Gt + fl * 1024 + u * 8;
  const f32x4 Z = {0.f, 0.f, 0.f, 0.f};

  f32x4  acc[4] = {};
  f32x4  xc[2][2], xn[2][2];
  bf16x8 bc[4][2], bn[4][2];

#pragma unroll
  for (int kt = 0; kt < 2; kt++) {        // kk = 0: no shift, always valid
    xc[kt][0] = *(const f32x4*)(xp + kt * 32);
    xc[kt][1] = *(const f32x4*)(xp + kt * 32 + 4);
  }
#pragma unroll
  for (int ct = 0; ct < 4; ct++)
#pragma unroll
    for (int kt = 0; kt < 2; kt++)
      bc[ct][kt] = *(const bf16x8*)(wp + ct * 16384 + kt * 32);

#pragma unroll
  for (int kk = 0; kk < 16; kk++) {
    if (kk < 15) {
      const int k1 = kk + 1;
      const bool ok = (tloc >= k1);
      const float* ap = xp - (ok ? k1 * 64 : 0);   // clamped-safe address
#pragma unroll
      for (int kt = 0; kt < 2; kt++) {
        f32x4 v0 = *(const f32x4*)(ap + kt * 32);
        f32x4 v1 = *(const f32x4*)(ap + kt * 32 + 4);
        xn[kt][0] = ok ? v0 : Z;
        xn[kt][1] = ok ? v1 : Z;
      }
#pragma unroll
      for (int ct = 0; ct < 4; ct++)
#pragma unroll
        for (int kt = 0; kt < 2; kt++)
          bn[ct][kt] = *(const bf16x8*)(wp + ct * 16384 + k1 * 64 + kt * 32);
    }
    bf16x8 af[2];
#pragma unroll
    for (int kt = 0; kt < 2; kt++)
#pragma unroll
      for (int j = 0; j < 4; j++) {
        af[kt][j]     = (__bf16)xc[kt][0][j];
        af[kt][j + 4] = (__bf16)xc[kt][1][j];
      }
#pragma unroll
    for (int ct = 0; ct < 4; ct++) {
      acc[ct] = MFMA(af[0], bc[ct][0], acc[ct]);
      acc[ct] = MFMA(af[1], bc[ct][1], acc[ct]);
    }
    if (kk < 15) {
#pragma unroll
      for (int kt = 0; kt < 2; kt++) { xc[kt][0] = xn[kt][0]; xc[kt][1] = xn[kt][1]; }
#pragma unroll
      for (int ct = 0; ct < 4; ct++) { bc[ct][0] = bn[ct][0]; bc[ct][1] = bn[ct][1]; }
    }
  }

  const int rowC = blockIdx.x * 64 + w * 16 + u * 4;
#pragma unroll
  for (int ct = 0; ct < 4; ct++)
#pragma unroll
    for (int r = 0; r < 4; r++)
      states[(size_t)(rowC + r) * 64 + ct * 16 + fl] = (__bf16)acc[ct][r];
}

// ---------------- k_fin: r_fin/i_fin = sum_k beta[2047-k] @ C_k (f32) ----------------
// grid 16 = (b, part); 64 threads = f.
__global__ __launch_bounds__(64) void k_fin(const float* __restrict__ beta,
                                            const float* __restrict__ CkR,
                                            const float* __restrict__ CkI,
                                            float* __restrict__ outp) {
  const int b = blockIdx.x >> 1, part = blockIdx.x & 1;
  const int f = threadIdx.x;
  const float* C = (part ? CkI : CkR) + f * 64;
  float a0 = 0.f, a1 = 0.f, a2 = 0.f, a3 = 0.f;
#pragma unroll
  for (int k = 0; k < KTR; k++) {
    const float* br = beta + (size_t)(b * S_ + (S_ - 1) - k) * 64;
    const float* Ck = C + k * 4096;
#pragma unroll
    for (int e = 0; e < 64; e += 4) {
      a0 += br[e]     * Ck[e];
      a1 += br[e + 1] * Ck[e + 1];
      a2 += br[e + 2] * Ck[e + 2];
      a3 += br[e + 3] * Ck[e + 3];
    }
  }
  outp[YSZ + part * 512 + b * 64 + f] = a0 + a1 + a2 + a3;
}

// ---------------- k_y: y = states @ w_out^T fused with LayerNorm ----------------
__global__ __launch_bounds__(256) void k_y(const __bf16* __restrict__ states,
                                           const __bf16* __restrict__ wob,
                                           const float* __restrict__ gamma,
                                           const float* __restrict__ lbeta,
                                           float* __restrict__ y) {
  const int tid = threadIdx.x;
  const int w = tid >> 6, lane = tid & 63;
  const int u = lane >> 4, fl = lane & 15;
  const int rowbase = blockIdx.x * 32;

  bf16x8 ar[2][2];
#pragma unroll
  for (int rt = 0; rt < 2; rt++)
#pragma unroll
    for (int kt = 0; kt < 2; kt++)
      ar[rt][kt] = *(const bf16x8*)(states + (size_t)(rowbase + rt * 16 + fl) * 64 + kt * 32 + u * 8);

  const __bf16* wp = wob + (size_t)(w * 256 + fl) * 64 + u * 8;

  f32x4 acc[2][16] = {};
  bf16x8 bcur[2], bnext[2];
#pragma unroll
  for (int kt = 0; kt < 2; kt++) bcur[kt] = *(const bf16x8*)(wp + kt * 32);

#pragma unroll
  for (int ct = 0; ct < 16; ct++) {
    if (ct < 15) {
#pragma unroll
      for (int kt = 0; kt < 2; kt++) bnext[kt] = *(const bf16x8*)(wp + (ct + 1) * 1024 + kt * 32);
    }
#pragma unroll
    for (int rt = 0; rt < 2; rt++) {
      acc[rt][ct] = MFMA(ar[rt][0], bcur[0], acc[rt][ct]);
      acc[rt][ct] = MFMA(ar[rt][1], bcur[1], acc[rt][ct]);
    }
    if (ct < 15) { bcur[0] = bnext[0]; bcur[1] = bnext[1]; }
  }

  float s1[2][4], s2[2][4];
#pragma unroll
  for (int rt = 0; rt < 2; rt++)
#pragma unroll
    for (int r = 0; r < 4; r++) {
      float a = 0.f, q = 0.f;
#pragma unroll
      for (int ct = 0; ct < 16; ct++) {
        const float v = acc[rt][ct][r];
        a += v; q += v * v;
      }
      s1[rt][r] = a; s2[rt][r] = q;
    }
#pragma unroll
  for (int m = 1; m < 16; m <<= 1) {
#pragma unroll
    for (int rt = 0; rt < 2; rt++)
#pragma unroll
      for (int r = 0; r < 4; r++) {
        s1[rt][r] += __shfl_xor(s1[rt][r], m, 64);
        s2[rt][r] += __shfl_xor(s2[rt][r], m, 64);
      }
  }
  __shared__ float pS1[4][32];
  __shared__ float pS2[4][32];
  if (fl == 0) {
#pragma unroll
    for (int rt = 0; rt < 2; rt++)
#pragma unroll
      for (int r = 0; r < 4; r++) {
        pS1[w][rt * 16 + u * 4 + r] = s1[rt][r];
        pS2[w][rt * 16 + u * 4 + r] = s2[rt][r];
      }
  }
  __syncthreads();
  float mu[2][4], rs[2][4];
#pragma unroll
  for (int rt = 0; rt < 2; rt++)
#pragma unroll
    for (int r = 0; r < 4; r++) {
      const int rl = rt * 16 + u * 4 + r;
      float S1 = 0.f, S2 = 0.f;
#pragma unroll
      for (int ww = 0; ww < 4; ww++) { S1 += pS1[ww][rl]; S2 += pS2[ww][rl]; }
      const float m  = S1 * (1.0f / 1024.0f);
      const float va = S2 * (1.0f / 1024.0f) - m * m;
      mu[rt][r] = m;
      rs[rt][r] = rsqrtf(va + 1e-5f);
    }
#pragma unroll
  for (int ct = 0; ct < 16; ct++) {
    const int d = w * 256 + ct * 16 + fl;
    const float gv = gamma[d], bv = lbeta[d];
#pragma unroll
    for (int rt = 0; rt < 2; rt++)
#pragma unroll
      for (int r = 0; r < 4; r++) {
        const float v = (acc[rt][ct][r] - mu[rt][r]) * rs[rt][r] * gv + bv;
        y[(size_t)(rowbase + rt * 16 + u * 4 + r) * 1024 + d] = v;
      }
  }
}

extern "C" void kernel_launch(void* const* d_in, const int* in_sizes, int n_in,
                              void* d_out, int out_size, void* d_ws, size_t ws_size,
                              hipStream_t stream) {
  const float* x         = (const float*)d_in[0];
  const float* alpha     = (const float*)d_in[1];
  const float* omega     = (const float*)d_in[2];
  const float* w_in      = (const float*)d_in[3];
  const float* w_out     = (const float*)d_in[4];
  const float* resonance = (const float*)d_in[5];
  const float* ln_g      = (const float*)d_in[6];
  const float* ln_b      = (const float*)d_in[7];
  float* out = (float*)d_out;

  char* ws = (char*)d_ws;
  float*  beta   = (float*)ws;                                    // 4 MB
  __bf16* states = (__bf16*)(ws + (4u << 20));                    // 2 MB
  __bf16* winb   = (__bf16*)(ws + (6u << 20));                    // 128 KB
  __bf16* wob    = (__bf16*)(ws + (6u << 20) + (128u << 10));     // 128 KB
  __bf16* Gt     = (__bf16*)(ws + (6u << 20) + (256u << 10));     // 128 KB
  float*  CkR    = (float*) (ws + (6u << 20) + (384u << 10));     // 256 KB
  float*  CkI    = (float*) (ws + (6u << 20) + (640u << 10));     // 256 KB

  k_setup  <<<256, 256, 0, stream>>>(w_in, w_out, winb, wob);
  k_impulse<<<4,   64,  0, stream>>>(resonance, alpha, omega, Gt, CkR, CkI);
  k_beta   <<<256, 256, 0, stream>>>(x, winb, beta);
  k_conv   <<<256, 256, 0, stream>>>(beta, Gt, states);
  k_fin    <<<16,  64,  0, stream>>>(beta, CkR, CkI, out);
  k_y      <<<512, 256, 0, stream>>>(states, wob, ln_g, ln_b, out);
}